// Round 7
// baseline (108.539 us; speedup 1.0000x reference)
//
#include <hip/hip_runtime.h>

typedef short  s4  __attribute__((ext_vector_type(4)));   // 4 bf16 in 2 VGPRs
typedef float  f4  __attribute__((ext_vector_type(4)));
typedef unsigned int u2v __attribute__((ext_vector_type(2)));
typedef unsigned int uint32;
typedef unsigned short ushort16;

#define NF      10
#define CIN     64
#define NTOT    8192              // T*H*W
#define HW      1024
#define FPAD    16                // feature dim padded for MFMA K
#define MSPLIT  32                // m-splits (partials -> reduce kernel)
#define MCHUNK  (NTOT / MSPLIT)   // 256 m per block
#define PSTRIDE 16                // f-stride of partial buffer
#define NT      8                 // 16-n tiles per wave (128 n)

// ---- v_mfma_f32_16x16x16_bf16: D[i][j], i=4*(lane/16)+reg (M), j=lane%16 (N)
//      A[i][k]: i=lane%16, k=4*(lane/16)+jj ; B[k][j]: j=lane%16, k=4*(lane/16)+jj
//      D layout == B layout -> relu'd scores feed PV mfma with zero shuffles.
//      (This D==B k-chunk-of-4 match is unique to the K=16 shape; verified
//      end-to-end R2-R6.)
// UNCONDITIONAL builtin this round: if this fails to compile, the asm
// fallback was live in R2-R6 and was the serializer. (ISA doc lists the
// instruction for gfx950, so the builtin should exist.)
#define MFMA16(a, b, c) __builtin_amdgcn_mfma_f32_16x16x16bf16_1k((a), (b), (c), 0, 0, 0)

static __device__ inline ushort16 f32_to_bf16_rne(float x) {
    uint32 u = __builtin_bit_cast(uint32, x);
    u = (u + 0x7fffu + ((u >> 16) & 1u)) >> 16;
    return (ushort16)u;
}

// ---------------------------------------------------------------------------
// Stage 1: projections -> bf16 workspace. Identical to R4-R6.
// ---------------------------------------------------------------------------
__global__ __launch_bounds__(64) void qkv_kernel(
    const float* __restrict__ in1, const float* __restrict__ in2,
    const float* __restrict__ w1, const float* __restrict__ b1,
    const float* __restrict__ w2, const float* __restrict__ b2,
    const float* __restrict__ w3, const float* __restrict__ b3,
    ushort16* __restrict__ qb, ushort16* __restrict__ kb,
    ushort16* __restrict__ vtile)
{
    __shared__ ushort16 lvs[64][FPAD];                 // v staging, 2 KB

    const int tid = threadIdx.x;
    const int n  = blockIdx.x * 64 + tid;
    const int t  = n >> 10;
    const int hw = n & 1023;

    if (blockIdx.y == 0) {
        const float* p = in1 + (size_t)t * (CIN * HW) + hw;
        float a[CIN];
#pragma unroll
        for (int c = 0; c < CIN; ++c) a[c] = p[c * HW];   // 64 loads in flight

        float aq[NF], av[NF];
#pragma unroll
        for (int f = 0; f < NF; ++f) { aq[f] = b1[f]; av[f] = b3[f]; }
#pragma unroll
        for (int c = 0; c < CIN; ++c) {
#pragma unroll
            for (int f = 0; f < NF; ++f) {
                aq[f] = fmaf(w1[f * CIN + c], a[c], aq[f]);
                av[f] = fmaf(w3[f * CIN + c], a[c], av[f]);
            }
        }
        ushort16 row[FPAD];
#pragma unroll
        for (int f = 0; f < NF; ++f) row[f] = f32_to_bf16_rne(aq[f]);
#pragma unroll
        for (int f = NF; f < FPAD; ++f) row[f] = 0;       // K-pad MUST be zero
        ushort16* dq = qb + (size_t)n * FPAD;
        ((uint4*)dq)[0] = ((const uint4*)row)[0];
        ((uint4*)dq)[1] = ((const uint4*)row)[1];

        // v: stage to LDS, then coalesced fragment-order store
#pragma unroll
        for (int f = 0; f < NF; ++f) lvs[tid][f] = f32_to_bf16_rne(av[f]);
#pragma unroll
        for (int f = NF; f < FPAD; ++f) lvs[tid][f] = 0;
        __syncthreads();
        const int quad = (tid & 15) >> 2;
        const int tloc = tid >> 4;
        ushort16 obuf[16];
#pragma unroll
        for (int e = 0; e < 16; ++e) {
            int f  = ((tid & 3) * 4 + (e >> 2)) & 15;
            int mi = quad * 4 + (e & 3);
            obuf[e] = lvs[tloc * 16 + mi][f];
        }
        ushort16* dv = vtile + (size_t)blockIdx.x * 1024 + tid * 16;
        ((uint4*)dv)[0] = ((const uint4*)obuf)[0];
        ((uint4*)dv)[1] = ((const uint4*)obuf)[1];
    } else {
        const float* p = in2 + (size_t)t * (CIN * HW) + hw;
        float a[CIN];
#pragma unroll
        for (int c = 0; c < CIN; ++c) a[c] = p[c * HW];

        float ak[NF];
#pragma unroll
        for (int f = 0; f < NF; ++f) ak[f] = b2[f];
#pragma unroll
        for (int c = 0; c < CIN; ++c) {
#pragma unroll
            for (int f = 0; f < NF; ++f) ak[f] = fmaf(w2[f * CIN + c], a[c], ak[f]);
        }
        ushort16 row[FPAD];
#pragma unroll
        for (int f = 0; f < NF; ++f) row[f] = f32_to_bf16_rne(ak[f]);
#pragma unroll
        for (int f = NF; f < FPAD; ++f) row[f] = 0;
        ushort16* dk = kb + (size_t)n * FPAD;
        ((uint4*)dk)[0] = ((const uint4*)row)[0];
        ((uint4*)dk)[1] = ((const uint4*)row)[1];
    }
}

// ---------------------------------------------------------------------------
// Stage 2: MFMA attention, PHASE-SEPARATED inner step this round:
//   phase A: 8 independent QK MFMAs back-to-back (latencies overlap)
//   phase B: 48 VALU relu+pack ops (all sc results long retired)
//   phase C: 8 independent PV MFMAs
// One kf/vf pair feeds 16 MFMAs; unconditional next-step prefetch (last-step
// over-read lands in ws padding -> harmless, never used).
// grid (NTOT/512, MSPLIT) = (16,32) = 512 blocks, block 256 (8 waves/CU).
// ---------------------------------------------------------------------------
__global__ __launch_bounds__(256) void attn_mfma_kernel(
    const ushort16* __restrict__ qb, const ushort16* __restrict__ kb,
    const ushort16* __restrict__ vtile, float* __restrict__ pws)
{
    const int lane = threadIdx.x & 63;
    const int wid  = threadIdx.x >> 6;
    const int row  = lane & 15;
    const int quad = lane >> 4;
    const int nb   = blockIdx.x * 512 + wid * (NT * 16);   // wave's 128-n base
    const int m0   = blockIdx.y * MCHUNK;

    s4 qf[NT];
#pragma unroll
    for (int g = 0; g < NT; ++g)
        qf[g] = *(const s4*)(qb + (size_t)(nb + g * 16 + row) * FPAD + 4 * quad);

    const s4* kp = (const s4*)(kb + (size_t)(m0 + row) * FPAD + 4 * quad);
    const s4* vp = (const s4*)(vtile + (size_t)(m0 >> 4) * 256) + lane;

    f4 acc[NT];
#pragma unroll
    for (int g = 0; g < NT; ++g) acc[g] = (f4){0.f, 0.f, 0.f, 0.f};
    const f4 zero = {0.f, 0.f, 0.f, 0.f};

    s4 kf = kp[0];
    s4 vf = vp[0];
    for (int s = 0; s < MCHUNK / 16; ++s) {
        // unconditional prefetch (s=last over-reads into adjacent ws, unused)
        s4 kf_n = kp[(s + 1) * 64];
        s4 vf_n = vp[(s + 1) * 64];

        // ---- phase A: all QK MFMAs, independent, back-to-back
        f4 sc[NT];
#pragma unroll
        for (int g = 0; g < NT; ++g)
            sc[g] = MFMA16(kf, qf[g], zero);          // S'[m][nb+16g+row]

        // ---- phase B: relu + truncate-pack f32->bf16 (6 VALU per g)
        s4 pb[NT];
#pragma unroll
        for (int g = 0; g < NT; ++g) {
            float r0 = fmaxf(sc[g][0], 0.f), r1 = fmaxf(sc[g][1], 0.f);
            float r2 = fmaxf(sc[g][2], 0.f), r3 = fmaxf(sc[g][3], 0.f);
            uint32 lo = __builtin_amdgcn_perm(__builtin_bit_cast(uint32, r1),
                                              __builtin_bit_cast(uint32, r0), 0x07060302u);
            uint32 hi = __builtin_amdgcn_perm(__builtin_bit_cast(uint32, r3),
                                              __builtin_bit_cast(uint32, r2), 0x07060302u);
            pb[g] = __builtin_bit_cast(s4, (u2v){lo, hi});
        }

        // ---- phase C: all PV MFMAs, independent chains per g
#pragma unroll
        for (int g = 0; g < NT; ++g)
            acc[g] = MFMA16(vf, pb[g], acc[g]);       // out'[f=4q+r][nb+16g+row]

        kf = kf_n;
        vf = vf_n;
    }

    const int fbase = 4 * quad;
#pragma unroll
    for (int g = 0; g < NT; ++g) {
        const int n = nb + g * 16 + row;
#pragma unroll
        for (int r = 0; r < 4; ++r) {
            int f = fbase + r;
            if (f < NF)
                pws[((size_t)blockIdx.y * PSTRIDE + f) * NTOT + n] = acc[g][r];
        }
    }
}

// ---------------------------------------------------------------------------
// Stage 3: sum MSPLIT partials, write out[t][f][h][w]. grid 320 x 256.
// ---------------------------------------------------------------------------
__global__ __launch_bounds__(256) void reduce_kernel(
    const float* __restrict__ pws, float* __restrict__ out)
{
    const int gid = blockIdx.x * 256 + threadIdx.x;    // 0 .. NF*NTOT-1
    const int f = gid >> 13;                           // / NTOT
    const int n = gid & (NTOT - 1);
    float s = 0.f;
#pragma unroll
    for (int y = 0; y < MSPLIT; ++y)
        s += pws[((size_t)y * PSTRIDE + f) * NTOT + n];
    const int t = n >> 10, hw = n & 1023;
    out[(size_t)t * (NF * HW) + f * HW + hw] = s;
}

extern "C" void kernel_launch(void* const* d_in, const int* in_sizes, int n_in,
                              void* d_out, int out_size, void* d_ws, size_t ws_size,
                              hipStream_t stream)
{
    const float* in1 = (const float*)d_in[0];
    const float* in2 = (const float*)d_in[1];
    const float* w1  = (const float*)d_in[2];
    const float* b1  = (const float*)d_in[3];
    const float* w2  = (const float*)d_in[4];
    const float* b2  = (const float*)d_in[5];
    const float* w3  = (const float*)d_in[6];
    const float* b3  = (const float*)d_in[7];

    // ws layout: qb | kb | vtile (256 KB each, bf16) | pws (16 MB fp32)
    ushort16* qb    = (ushort16*)d_ws;
    ushort16* kb    = qb + (size_t)NTOT * FPAD;
    ushort16* vtile = kb + (size_t)NTOT * FPAD;
    float*    pws   = (float*)(vtile + (size_t)NTOT * FPAD);
    float*    out   = (float*)d_out;

    qkv_kernel<<<dim3(NTOT / 64, 2), 64, 0, stream>>>(
        in1, in2, w1, b1, w2, b2, w3, b3, qb, kb, vtile);

    attn_mfma_kernel<<<dim3(NTOT / 512, MSPLIT), 256, 0, stream>>>(qb, kb, vtile, pws);

    reduce_kernel<<<dim3(NF * NTOT / 256), 256, 0, stream>>>(pws, out);
}

// Round 8
// 104.049 us; speedup vs baseline: 1.0432x; 1.0432x over previous
//
#include <hip/hip_runtime.h>

typedef short  sv8 __attribute__((ext_vector_type(8)));   // 8 bf16 (4 VGPRs)
typedef float  fv16 __attribute__((ext_vector_type(16))); // MFMA C/D
typedef unsigned int uv4 __attribute__((ext_vector_type(4)));
typedef unsigned int uint32;
typedef unsigned short ushort16;

#define NF      10
#define CIN     64
#define NTOT    8192              // T*H*W
#define HW      1024
#define FPAD    16                // feature dim padded for MFMA K
#define MSPLIT  16                // m-splits (partials -> reduce kernel)
#define MCHUNK  (NTOT / MSPLIT)   // 512 m per block
#define PSTRIDE 16                // f-stride of partial buffer

// Native gfx950 shape: v_mfma_f32_32x32x16_bf16 (measured 2382 TF, ~8cyc).
//   C/D: col=lane&31, row=(reg&3)+8*(reg>>2)+4*(lane>>5)   [measured m74/m101]
//   A:   i=lane&31,   k=8*(lane>>5)+j  (j=0..7)            [inferred, std pattern]
//   B:   j=lane&31,   k=8*(lane>>5)+jj                     [inferred, mirror of A]
#define MFMA32(a, b, c) __builtin_amdgcn_mfma_f32_32x32x16_bf16((a), (b), (c), 0, 0, 0)

static __device__ inline ushort16 f32_to_bf16_rne(float x) {
    uint32 u = __builtin_bit_cast(uint32, x);
    u = (u + 0x7fffu + ((u >> 16) & 1u)) >> 16;
    return (ushort16)u;
}

// ---------------------------------------------------------------------------
// Stage 1: projections -> bf16 workspace.
//   qb[n][16], kb[n][16] row-major bf16 (f-pad zeroed) — serve as 32x32x16
//   B/A frags directly: lane reads row (base+col), bytes [h*16, h*16+16).
//   vfrag: V in PV A-frag order. Per 32-m tile tau, two 1KB frags (fs=0,1):
//     byte addr = tau*2048 + fs*1024 + (h*32+f)*16, holding 8 bf16 =
//     v[f][m = 32*tau + fs*16 + 8h + j], j=0..7. f>=10 slots zero.
// grid (NTOT/64, 2), block 64.
// ---------------------------------------------------------------------------
__global__ __launch_bounds__(64) void qkv_kernel(
    const float* __restrict__ in1, const float* __restrict__ in2,
    const float* __restrict__ w1, const float* __restrict__ b1,
    const float* __restrict__ w2, const float* __restrict__ b2,
    const float* __restrict__ w3, const float* __restrict__ b3,
    ushort16* __restrict__ qb, ushort16* __restrict__ kb,
    ushort16* __restrict__ vfrag)
{
    __shared__ ushort16 lvs[64][FPAD];                 // v staging, 2 KB

    const int tid = threadIdx.x;
    const int n  = blockIdx.x * 64 + tid;
    const int t  = n >> 10;
    const int hw = n & 1023;

    if (blockIdx.y == 0) {
        const float* p = in1 + (size_t)t * (CIN * HW) + hw;
        float a[CIN];
#pragma unroll
        for (int c = 0; c < CIN; ++c) a[c] = p[c * HW];   // 64 loads in flight

        float aq[NF], av[NF];
#pragma unroll
        for (int f = 0; f < NF; ++f) { aq[f] = b1[f]; av[f] = b3[f]; }
#pragma unroll
        for (int c = 0; c < CIN; ++c) {
#pragma unroll
            for (int f = 0; f < NF; ++f) {
                aq[f] = fmaf(w1[f * CIN + c], a[c], aq[f]);
                av[f] = fmaf(w3[f * CIN + c], a[c], av[f]);
            }
        }
        ushort16 row[FPAD];
#pragma unroll
        for (int f = 0; f < NF; ++f) row[f] = f32_to_bf16_rne(aq[f]);
#pragma unroll
        for (int f = NF; f < FPAD; ++f) row[f] = 0;       // K-pad MUST be zero
        ushort16* dq = qb + (size_t)n * FPAD;
        ((uint4*)dq)[0] = ((const uint4*)row)[0];
        ((uint4*)dq)[1] = ((const uint4*)row)[1];

        // v: stage to LDS, then emit PV A-fragments
#pragma unroll
        for (int f = 0; f < NF; ++f) lvs[tid][f] = f32_to_bf16_rne(av[f]);
        __syncthreads();
        const int l  = tid & 31;                          // f-slot
        const int tl = tid >> 5;                          // local 32-m tile
        char* base = (char*)vfrag + ((size_t)(blockIdx.x * 2 + tl)) * 2048;
#pragma unroll
        for (int fs = 0; fs < 2; ++fs) {
#pragma unroll
            for (int hh = 0; hh < 2; ++hh) {
                ushort16 buf[8];
#pragma unroll
                for (int j = 0; j < 8; ++j)
                    buf[j] = (l < NF) ? lvs[32 * tl + fs * 16 + 8 * hh + j][l]
                                      : (ushort16)0;
                *(uint4*)(base + fs * 1024 + (hh * 32 + l) * 16) =
                    *(const uint4*)buf;
            }
        }
    } else {
        const float* p = in2 + (size_t)t * (CIN * HW) + hw;
        float a[CIN];
#pragma unroll
        for (int c = 0; c < CIN; ++c) a[c] = p[c * HW];

        float ak[NF];
#pragma unroll
        for (int f = 0; f < NF; ++f) ak[f] = b2[f];
#pragma unroll
        for (int c = 0; c < CIN; ++c) {
#pragma unroll
            for (int f = 0; f < NF; ++f) ak[f] = fmaf(w2[f * CIN + c], a[c], ak[f]);
        }
        ushort16 row[FPAD];
#pragma unroll
        for (int f = 0; f < NF; ++f) row[f] = f32_to_bf16_rne(ak[f]);
#pragma unroll
        for (int f = NF; f < FPAD; ++f) row[f] = 0;
        ushort16* dk = kb + (size_t)n * FPAD;
        ((uint4*)dk)[0] = ((const uint4*)row)[0];
        ((uint4*)dk)[1] = ((const uint4*)row)[1];
    }
}

// ---------------------------------------------------------------------------
// Stage 2: native 32x32x16 MFMA attention. Per 32m-step:
//   S = mfma32(Kfrag, Qfrag)          -> 32m x 32n scores (1 MFMA)
//   relu + pack to bf16 pairs p[0..7] -> cross-half exchange (shfl_xor 32)
//   acc1 += mfma32(Vfrag_lo, B1) ; acc2 += mfma32(Vfrag_hi, B2)
// grid (64, MSPLIT) = 1024 blocks, block 256 (4 waves: one 32-n tile each).
// ---------------------------------------------------------------------------
__global__ __launch_bounds__(256) void attn_mfma_kernel(
    const ushort16* __restrict__ qb, const ushort16* __restrict__ kb,
    const ushort16* __restrict__ vfrag, float* __restrict__ pws)
{
    const int lane = threadIdx.x & 63;
    const int wid  = threadIdx.x >> 6;
    const int col  = lane & 31;                        // n_local / m-row
    const int h    = lane >> 5;                        // k-half
    const int n0   = (blockIdx.x * 4 + wid) * 32;
    const int m0   = blockIdx.y * MCHUNK;

    // Q B-frag (loop-invariant): qb[n0+col], bytes [16h, 16h+16)
    const uint4 qraw = *(const uint4*)((const char*)qb + (size_t)(n0 + col) * 32 + h * 16);
    const sv8 qf = __builtin_bit_cast(sv8, qraw);

    const char* kbase = (const char*)kb + (size_t)(m0 + col) * 32 + h * 16;   // +1024/step
    const char* vbase = (const char*)vfrag + (size_t)(m0 >> 5) * 2048 + lane * 16; // +2048/step

    fv16 zerov, acc1, acc2;
#pragma unroll
    for (int i = 0; i < 16; ++i) { zerov[i] = 0.f; acc1[i] = 0.f; acc2[i] = 0.f; }

    uint4 kf = *(const uint4*)kbase;
    uint4 v1 = *(const uint4*)vbase;
    uint4 v2 = *(const uint4*)(vbase + 1024);

    for (int s = 0; s < MCHUNK / 32; ++s) {
        // unconditional prefetch (last-step over-read lands in ws, unused)
        uint4 kf_n = *(const uint4*)(kbase + (size_t)(s + 1) * 1024);
        uint4 v1_n = *(const uint4*)(vbase + (size_t)(s + 1) * 2048);
        uint4 v2_n = *(const uint4*)(vbase + (size_t)(s + 1) * 2048 + 1024);

        fv16 S = MFMA32(__builtin_bit_cast(sv8, kf), qf, zerov);

        // relu + truncate-pack: p[i] = (bf16(S[2i]) , bf16(S[2i+1]))
        // reg r -> m = (r&3) + 8*(r>>2) + 4h
        uint32 p[8];
#pragma unroll
        for (int i = 0; i < 8; ++i) {
            float e0 = fmaxf(S[2 * i], 0.f);
            float e1 = fmaxf(S[2 * i + 1], 0.f);
            p[i] = __builtin_amdgcn_perm(__builtin_bit_cast(uint32, e1),
                                         __builtin_bit_cast(uint32, e0), 0x07060302u);
        }
        // partner half's pairs (lane^32: same n, other h)
        uint32 sw[8];
#pragma unroll
        for (int i = 0; i < 8; ++i)
            sw[i] = __shfl_xor((unsigned int)p[i], 32, 64);

        // B1 (k=m_local 0..15): h=0 -> [p0,p1,sw0,sw1]; h=1 -> [sw2,sw3,p2,p3]
        uv4 b1 = { h ? sw[2] : p[0], h ? sw[3] : p[1],
                   h ? p[2] : sw[0], h ? p[3] : sw[1] };
        // B2 (k=m_local 16..31): h=0 -> [p4,p5,sw4,sw5]; h=1 -> [sw6,sw7,p6,p7]
        uv4 b2 = { h ? sw[6] : p[4], h ? sw[7] : p[5],
                   h ? p[6] : sw[4], h ? p[7] : sw[5] };

        acc1 = MFMA32(__builtin_bit_cast(sv8, v1), __builtin_bit_cast(sv8, b1), acc1);
        acc2 = MFMA32(__builtin_bit_cast(sv8, v2), __builtin_bit_cast(sv8, b2), acc2);

        kf = kf_n; v1 = v1_n; v2 = v2_n;
    }

    // Epilogue: D[f][n]: f = (r&3)+8*(r>>2)+4h, n = n0+col
    const int n = n0 + col;
#pragma unroll
    for (int r = 0; r < 16; ++r) {
        int f = (r & 3) + 8 * (r >> 2) + 4 * h;
        if (f < NF)
            pws[((size_t)blockIdx.y * PSTRIDE + f) * NTOT + n] = acc1[r] + acc2[r];
    }
}

// ---------------------------------------------------------------------------
// Stage 3: sum MSPLIT partials, write out[t][f][h][w]. grid 320 x 256.
// ---------------------------------------------------------------------------
__global__ __launch_bounds__(256) void reduce_kernel(
    const float* __restrict__ pws, float* __restrict__ out)
{
    const int gid = blockIdx.x * 256 + threadIdx.x;    // 0 .. NF*NTOT-1
    const int f = gid >> 13;                           // / NTOT
    const int n = gid & (NTOT - 1);
    float s = 0.f;
#pragma unroll
    for (int y = 0; y < MSPLIT; ++y)
        s += pws[((size_t)y * PSTRIDE + f) * NTOT + n];
    const int t = n >> 10, hw = n & 1023;
    out[(size_t)t * (NF * HW) + f * HW + hw] = s;
}

extern "C" void kernel_launch(void* const* d_in, const int* in_sizes, int n_in,
                              void* d_out, int out_size, void* d_ws, size_t ws_size,
                              hipStream_t stream)
{
    const float* in1 = (const float*)d_in[0];
    const float* in2 = (const float*)d_in[1];
    const float* w1  = (const float*)d_in[2];
    const float* b1  = (const float*)d_in[3];
    const float* w2  = (const float*)d_in[4];
    const float* b2  = (const float*)d_in[5];
    const float* w3  = (const float*)d_in[6];
    const float* b3  = (const float*)d_in[7];

    // ws layout: qb (256K) | kb (256K) | vfrag (512K) | pws (8 MB fp32)
    ushort16* qb    = (ushort16*)d_ws;
    ushort16* kb    = qb + (size_t)NTOT * FPAD;
    ushort16* vfrag = kb + (size_t)NTOT * FPAD;
    float*    pws   = (float*)((char*)vfrag + 512 * 1024);
    float*    out   = (float*)d_out;

    qkv_kernel<<<dim3(NTOT / 64, 2), 64, 0, stream>>>(
        in1, in2, w1, b1, w2, b2, w3, b3, qb, kb, vfrag);

    attn_mfma_kernel<<<dim3(64, MSPLIT), 256, 0, stream>>>(qb, kb, vfrag, pws);

    reduce_kernel<<<dim3(NF * NTOT / 256), 256, 0, stream>>>(pws, out);
}